// Round 21
// baseline (77.317 us; speedup 1.0000x reference)
//
#include <hip/hip_runtime.h>

#define NN 100000
#define NE 1600000
#define DIN 128
#define DOUT 32
#define NBUK 391     // ceil(NN/256) buckets of 256 nodes
#define FILLB 500    // edge chunks (500*3200 = NE exactly)
#define CHUNK 3200   // edges per chunk (records region 128B-aligned)
#define CAP 8192     // LDS stage capacity per bucket (counts mean 4092, sd 64)
#define CAP_PAD 6144 // padded per-bucket srcs region (sum ceil8(deg): mean ~5050, sd ~70)
#define NTILES 6250  // NN/16 MFMA row-tiles
#define XWB 782      // ceil(6250 / 8 waves)

typedef unsigned short ushort_t;
typedef unsigned int uint_t;
typedef _Float16 f16x8 __attribute__((ext_vector_type(8)));
typedef float f32x4 __attribute__((ext_vector_type(4)));

static __device__ __forceinline__ ushort_t f2h_u(float f) {
    _Float16 h = (_Float16)f;
    ushort_t u;
    __builtin_memcpy(&u, &h, 2);
    return u;
}
static __device__ __forceinline__ float h2f(ushort_t us) {
    _Float16 h;
    __builtin_memcpy(&h, &us, 2);
    return (float)h;
}
// wave-level inclusive scan (64 lanes, no barriers)
static __device__ __forceinline__ int wave_scan(int v, int lane) {
#pragma unroll
    for (int off = 1; off < 64; off <<= 1) {
        int u = __shfl_up(v, off, 64);
        if (lane >= off) v += u;
    }
    return v;
}

// ===========================================================================
// k1: FUSED fill + xw.
// Blocks [0, FILLB): histogram -> 1-barrier wave scan -> LDS counting sort
//   (col re-read, L1-hot) -> uint4-COALESCED records write; chunk-local
//   offsets -> histmat.
// Blocks [FILLB, FILLB+XWB): xwsh[r] = f16(x[r] @ W) via MFMA. W is staged
//   ONCE per block into transposed f16 LDS (coalesced load, 8 KB); fragments
//   come from ds_read_b128 instead of 64 strided dword loads per thread.
// record = (row << 8) | (col & 255)
// ===========================================================================
__global__ __launch_bounds__(512)
void fill_xw_kernel(const int* __restrict__ row, const int* __restrict__ col,
                    int* __restrict__ histmat, unsigned int* __restrict__ records,
                    const float* __restrict__ x, const float* __restrict__ W,
                    ushort_t* __restrict__ xwsh) {
    __shared__ unsigned int stage[CHUNK];    // 12.8 KB (fill branch)
    __shared__ int hist[NBUK];
    __shared__ int lcur[NBUK];
    __shared__ int wsum[8];
    if (blockIdx.x < FILLB) {
        int t = threadIdx.x, blk = blockIdx.x;
        int lane = t & 63, wv = t >> 6;
        for (int bb = t; bb < NBUK; bb += 512) hist[bb] = 0;
        __syncthreads();
        int e0 = blk * CHUNK;
        for (int j = t; j < CHUNK; j += 512) atomicAdd(&hist[col[e0 + j] >> 8], 1);
        __syncthreads();
        int own = (t < NBUK) ? hist[t] : 0;
        int inc = wave_scan(own, lane);
        if (lane == 63) wsum[wv] = inc;
        __syncthreads();
        int wpre = 0;
#pragma unroll
        for (int w = 0; w < 8; ++w) wpre += (w < wv) ? wsum[w] : 0;
        int excl = inc + wpre - own;           // exclusive prefix; t==NBUK -> 3200
        if (t <= NBUK) {
            histmat[(size_t)blk * (NBUK + 1) + t] = excl;
            if (t < NBUK) lcur[t] = excl;
        }
        __syncthreads();
        for (int j = t; j < CHUNK; j += 512) {
            int e = e0 + j;
            int c = col[e];                    // L1-hot re-read
            int slot = atomicAdd(&lcur[c >> 8], 1);
            stage[slot] = ((unsigned int)row[e] << 8) | (unsigned int)(c & 255);
        }
        __syncthreads();
        uint4* dst = (uint4*)(records + (size_t)blk * CHUNK);
        const uint4* srcv = (const uint4*)stage;
        for (int j = t; j < CHUNK / 4; j += 512) dst[j] = srcv[j];
        return;
    }
    // ---- xw part: 8 waves x 16 rows; W staged to transposed f16 LDS ----
    __shared__ ushort_t WhtL[DOUT * DIN];      // 8 KB (xw branch)
    int t = threadIdx.x;
    int wv = t >> 6, lane = t & 63;
    // cooperative W stage: thread t loads W[k][c] for 8 consecutive i
    for (int i = t; i < DIN * DOUT; i += 512) {
        int k = i >> 5;          // 0..127 (row of W)
        int c = i & 31;          // 0..31  (col of W)
        WhtL[(size_t)c * DIN + k] = f2h_u(W[i]);   // coalesced read of W
    }
    __syncthreads();

    int wtile = (blockIdx.x - FILLB) * 8 + wv;
    if (wtile >= NTILES) return;           // uniform per wave
    int r0 = wtile * 16;
    int rowi = lane & 15;                  // A-row / B-col / D-col
    int kg = lane >> 4;                    // k-group (0..3)

    // B fragments from LDS (ds_read_b128)
    f16x8 bfrag[2][4];
#pragma unroll
    for (int t2 = 0; t2 < 2; ++t2)
#pragma unroll
        for (int ss = 0; ss < 4; ++ss)
            bfrag[t2][ss] = *(const f16x8*)(WhtL + (size_t)(t2 * 16 + rowi) * DIN + ss * 32 + kg * 8);

    const float* __restrict__ xr = x + (size_t)(r0 + rowi) * DIN;
    float4 xa[8];
#pragma unroll
    for (int ss = 0; ss < 4; ++ss) {
        xa[2 * ss]     = *(const float4*)(xr + ss * 32 + kg * 8);
        xa[2 * ss + 1] = *(const float4*)(xr + ss * 32 + kg * 8 + 4);
    }
    f16x8 afrag[4];
#pragma unroll
    for (int ss = 0; ss < 4; ++ss) {
        f16x8 a;
        a[0] = (_Float16)xa[2 * ss].x;     a[1] = (_Float16)xa[2 * ss].y;
        a[2] = (_Float16)xa[2 * ss].z;     a[3] = (_Float16)xa[2 * ss].w;
        a[4] = (_Float16)xa[2 * ss + 1].x; a[5] = (_Float16)xa[2 * ss + 1].y;
        a[6] = (_Float16)xa[2 * ss + 1].z; a[7] = (_Float16)xa[2 * ss + 1].w;
        afrag[ss] = a;
    }

    f32x4 acc0 = {0.f, 0.f, 0.f, 0.f};
    f32x4 acc1 = {0.f, 0.f, 0.f, 0.f};
#pragma unroll
    for (int ss = 0; ss < 4; ++ss) {
        acc0 = __builtin_amdgcn_mfma_f32_16x16x32_f16(afrag[ss], bfrag[0][ss], acc0, 0, 0, 0);
        acc1 = __builtin_amdgcn_mfma_f32_16x16x32_f16(afrag[ss], bfrag[1][ss], acc1, 0, 0, 0);
    }

#pragma unroll
    for (int j = 0; j < 4; ++j) {
        int orow = r0 + kg * 4 + j;
        xwsh[(size_t)orow * DOUT + rowi]      = f2h_u(acc0[j]);
        xwsh[(size_t)orow * DOUT + 16 + rowi] = f2h_u(acc1[j]);
    }
}

// ===========================================================================
// k2: per-bucket sort. Bucket b owns fixed region srcs[b*CAP_PAD..].
// Clamp-batched segment gather (8 reads in flight), per-wave privatized
// node histogram, 1-barrier wave scans, LDS counting sort into an
// 8-ALIGNED-PER-NODE padded layout (pads zero-filled), offe/dis,
// xwsh-scale epilogue. 391 blocks x 512.
// ===========================================================================
__global__ __launch_bounds__(512)
void sort_kernel(const int* __restrict__ histmat,
                 const unsigned int* __restrict__ records,
                 int* __restrict__ srcs, float* __restrict__ dis,
                 int2* __restrict__ offe, ushort_t* __restrict__ xwsh) {
    __shared__ unsigned int stage[CAP];  // 32 KB
    __shared__ int whist[8][256];        // 8 KB, per-wave private histograms
    __shared__ int lcur[256];
    __shared__ float disL[256];
    __shared__ int wsum[8];
    __shared__ int wsum2[4];
    int b = blockIdx.x, t = threadIdx.x;
    int lane = t & 63, wv = t >> 6;
    int s_off = 0, len = 0;
    if (t < FILLB) {
        s_off = histmat[(size_t)t * (NBUK + 1) + b];
        len = histmat[(size_t)t * (NBUK + 1) + b + 1] - s_off;
    }
    for (int i = t; i < 8 * 256; i += 512) ((int*)whist)[i] = 0;
    // 1-barrier scan of segment lengths
    int inc = wave_scan(len, lane);
    if (lane == 63) wsum[wv] = inc;
    __syncthreads();
    int wpre = 0, cnt = 0;
#pragma unroll
    for (int w = 0; w < 8; ++w) {
        wpre += (w < wv) ? wsum[w] : 0;
        cnt += wsum[w];
    }
    int pos = inc + wpre - len;

    // clamp-batched gather: 8 scattered reads in flight per thread
    const unsigned int* seg = records + (size_t)t * CHUNK + s_off;
    for (int k = 0; k < len; k += 8) {
        unsigned int v[8];
#pragma unroll
        for (int u = 0; u < 8; ++u) {
            int idx = (k + u < len) ? (k + u) : (len - 1);
            v[u] = seg[idx];
        }
#pragma unroll
        for (int u = 0; u < 8; ++u)
            if (k + u < len) {
                stage[pos + k + u] = v[u];
                atomicAdd(&whist[wv][v[u] & 255u], 1);
            }
    }
    __syncthreads();

    int d = 0;
    if (t < 256) {
#pragma unroll
        for (int w = 0; w < 8; ++w) d += whist[w][t];
    }
    int pd = (d + 7) & ~7;               // padded degree (8-aligned region)
    // 1-barrier scan over the 256 padded degrees (4 waves)
    int inc2 = wave_scan((t < 256) ? pd : 0, lane);
    if (t < 256 && lane == 63) wsum2[wv] = inc2;
    __syncthreads();
    int sbase = b * CAP_PAD;
    if (t < 256) {
        int wpre2 = 0;
#pragma unroll
        for (int w = 0; w < 4; ++w) wpre2 += (w < wv) ? wsum2[w] : 0;
        int excl = inc2 + wpre2 - pd;    // 8-aligned start (relative)
        float dv = rsqrtf((float)(d + 1));
        disL[t] = dv;
        int n = (b << 8) + t;
        if (n < NN) {
            dis[n] = dv;
            offe[n] = make_int2(sbase + excl, sbase + excl + d);
        }
        lcur[t] = excl;
        // zero-fill the pad slots (safe index 0 for masked int4 gathers)
        for (int k = d; k < pd; ++k) srcs[sbase + excl + k] = 0;
    }
    __syncthreads();
    for (int j = t; j < cnt; j += 512) {
        unsigned int rec = stage[j];
        int slot = atomicAdd(&lcur[rec & 255u], 1);
        srcs[sbase + slot] = (int)(rec >> 8);
    }
    // epilogue: scale this bucket's xwsh rows by dis (coalesced u32 r/m/w)
    int n0 = b << 8;
    for (int idx = t; idx < 256 * 16; idx += 512) {
        int loc = idx >> 4;
        int n = n0 + loc;
        if (n >= NN) break;
        uint_t* p = (uint_t*)(xwsh + ((size_t)n << 5)) + (idx & 15);
        uint_t v = *p;
        float dv = disL[loc];
        float lo = h2f((ushort_t)(v & 0xffffu)) * dv;
        float hi = h2f((ushort_t)(v >> 16)) * dv;
        *p = (uint_t)f2h_u(lo) | ((uint_t)f2h_u(hi) << 16);
    }
}

// ===========================================================================
// k3: aggregate, zero-reduce layout, 8-wide batched. Half-wave (32 lanes)
// = one node; lane owns one output dim. Per round: TWO aligned int4 loads
// fetch the 8 srcs (regions 8-aligned; pads zero -> safe), 8 independent
// xwsh gathers, masked accumulate. offs/ends as one int2 load.
// ===========================================================================
__global__ __launch_bounds__(256)
void aggregate_kernel(const int2* __restrict__ offe, const int* __restrict__ srcs,
                      const float* __restrict__ dis, const ushort_t* __restrict__ xwsh,
                      const float* __restrict__ bias, float* __restrict__ out) {
    int gw = (int)((blockIdx.x * (long long)blockDim.x + threadIdx.x) >> 6);
    int half = (threadIdx.x >> 5) & 1;
    int wid = gw * 2 + half;
    if (wid >= NN) return;
    int d = threadIdx.x & 31;

    int2 se = offe[wid];
    int s = se.x, e = se.y;
    float acc = h2f(xwsh[((size_t)wid << 5) + d]);   // self-loop (scaled)
    for (int i = s; i < e; i += 8) {
        int4 ra = *(const int4*)(srcs + i);          // 8-aligned region
        int4 rb = *(const int4*)(srcs + i + 4);
        int r[8];
        r[0] = ra.x; r[1] = ra.y; r[2] = ra.z; r[3] = ra.w;
        r[4] = rb.x; r[5] = rb.y; r[6] = rb.z; r[7] = rb.w;
        ushort_t u[8];
#pragma unroll
        for (int k = 0; k < 8; ++k) u[k] = xwsh[((size_t)r[k] << 5) + d];
#pragma unroll
        for (int k = 0; k < 8; ++k) acc += (i + k < e) ? h2f(u[k]) : 0.f;
    }
    out[((size_t)wid << 5) + d] = dis[wid] * acc + bias[d];
}

// ===========================================================================
// Fallback path (R1) if workspace is too small
// ===========================================================================
__global__ void deg_count_kernel(const int* __restrict__ col, int* __restrict__ deg) {
    int e = blockIdx.x * blockDim.x + threadIdx.x;
    if (e < NE) atomicAdd(&deg[col[e]], 1);
}
__global__ void dis_kernel(const int* __restrict__ deg, float* __restrict__ dis) {
    int i = blockIdx.x * blockDim.x + threadIdx.x;
    if (i < NN) dis[i] = rsqrtf((float)(deg[i] + 1));
}
__global__ void xw_init_kernel(const float* __restrict__ x, const float* __restrict__ W,
                               const float* __restrict__ b, const float* __restrict__ dis,
                               float* __restrict__ xw, float* __restrict__ out) {
    __shared__ float Ws[DIN * DOUT];
    for (int i = threadIdx.x; i < DIN * DOUT; i += blockDim.x) Ws[i] = W[i];
    __syncthreads();
    int idx = blockIdx.x * blockDim.x + threadIdx.x;
    if (idx >= NN * DOUT) return;
    int n = idx >> 5;
    int d = idx & (DOUT - 1);
    const float* xr = x + (long long)n * DIN;
    float acc = 0.f;
#pragma unroll
    for (int k = 0; k < DIN; ++k) acc += xr[k] * Ws[k * DOUT + d];
    xw[idx] = acc;
    float di = dis[n];
    out[idx] = di * di * acc + b[d];
}
__global__ void scatter_kernel(const int* __restrict__ row, const int* __restrict__ col,
                               const float* __restrict__ dis, const float* __restrict__ xw,
                               float* __restrict__ out) {
    long long idx = (long long)blockIdx.x * blockDim.x + threadIdx.x;
    if (idx >= (long long)NE * DOUT) return;
    int e = (int)(idx >> 5);
    int d = (int)(idx & (DOUT - 1));
    int r = row[e];
    int c = col[e];
    atomicAdd(&out[c * DOUT + d], dis[r] * dis[c] * xw[r * DOUT + d]);
}

// ===========================================================================
extern "C" void kernel_launch(void* const* d_in, const int* in_sizes, int n_in,
                              void* d_out, int out_size, void* d_ws, size_t ws_size,
                              hipStream_t stream) {
    const float* x  = (const float*)d_in[0];
    const int*   ei = (const int*)d_in[1];
    const float* W  = (const float*)d_in[2];
    const float* b  = (const float*)d_in[3];
    float* out = (float*)d_out;

    const int* row = ei;       // edge_index[0] = source
    const int* col = ei + NE;  // edge_index[1] = target

    char* ws = (char*)d_ws;
    int*          histmat = (int*)(ws + 0);          //   500*392*4 = 784,000 B
    int2*         offe    = (int2*)(ws + 784128);    //   800,000 B
    float*        dis     = (float*)(ws + 1584128);  //   400,000 B
    unsigned int* records = (unsigned int*)(ws + 1984128);  // 6,400,000 B
    int*          srcs    = (int*)(ws + 8384128);    // 391*6144*4 = 9,609,216 B
    ushort_t*     xwsh    = (ushort_t*)(ws + 17993344);     // 6,400,000 B
    const size_t WS_NEEDED = 24393344ull;

    if (ws_size >= WS_NEEDED) {
        fill_xw_kernel<<<FILLB + XWB, 512, 0, stream>>>(row, col, histmat,
                                                        records, x, W, xwsh);
        sort_kernel<<<NBUK, 512, 0, stream>>>(histmat, records, srcs, dis,
                                              offe, xwsh);
        {
            long long waves = (NN + 1) / 2;             // 2 nodes per wave
            int bl = (int)((waves + 3) / 4);            // 4 waves per block
            aggregate_kernel<<<bl, 256, 0, stream>>>(offe, srcs, dis, xwsh, b, out);
        }
    } else {
        // fallback: atomic scatter path
        int* deg2 = (int*)(ws + 0);
        float* dis2 = (float*)(ws + 400128);
        float* xw = (float*)(ws + 800256);
        hipMemsetAsync(deg2, 0, NN * sizeof(int), stream);
        {
            int th = 256, bl = (NE + th - 1) / th;
            deg_count_kernel<<<bl, th, 0, stream>>>(col, deg2);
        }
        {
            int th = 256, bl = (NN + th - 1) / th;
            dis_kernel<<<bl, th, 0, stream>>>(deg2, dis2);
        }
        {
            long long total = (long long)NN * DOUT;
            int bl = (int)((total + 255) / 256);
            xw_init_kernel<<<bl, 256, 0, stream>>>(x, W, b, dis2, xw, out);
        }
        {
            long long total = (long long)NE * DOUT;
            int bl = (int)((total + 255) / 256);
            scatter_kernel<<<bl, 256, 0, stream>>>(row, col, dis2, xw, out);
        }
    }
}

// Round 22
// 72.634 us; speedup vs baseline: 1.0645x; 1.0645x over previous
//
#include <hip/hip_runtime.h>

#define NN 100000
#define NE 1600000
#define DIN 128
#define DOUT 32
#define NBUK 391     // ceil(NN/256) buckets of 256 nodes
#define FILLB 500    // edge chunks (500*3200 = NE exactly)
#define CHUNK 3200   // edges per chunk (records region 128B-aligned)
#define CAP 8192     // LDS stage capacity per bucket (counts mean 4092, sd 64)
#define CAP_PAD 6144 // padded per-bucket srcs region (sum ceil8(deg): mean ~5050, sd ~70)
#define NTILES 6250  // NN/16 MFMA row-tiles
#define XWB 782      // ceil(6250 / 8 waves)

typedef unsigned short ushort_t;
typedef unsigned int uint_t;
typedef _Float16 f16x8 __attribute__((ext_vector_type(8)));
typedef float f32x4 __attribute__((ext_vector_type(4)));

static __device__ __forceinline__ ushort_t f2h_u(float f) {
    _Float16 h = (_Float16)f;
    ushort_t u;
    __builtin_memcpy(&u, &h, 2);
    return u;
}
static __device__ __forceinline__ float h2f(ushort_t us) {
    _Float16 h;
    __builtin_memcpy(&h, &us, 2);
    return (float)h;
}
// wave-level inclusive scan (64 lanes, no barriers)
static __device__ __forceinline__ int wave_scan(int v, int lane) {
#pragma unroll
    for (int off = 1; off < 64; off <<= 1) {
        int u = __shfl_up(v, off, 64);
        if (lane >= off) v += u;
    }
    return v;
}

// ===========================================================================
// k1: FUSED fill + xw.  (R20 configuration — measured best)
// Blocks [0, FILLB): histogram -> 1-barrier wave scan -> LDS counting sort
//   (col re-read, L1-hot) -> uint4-COALESCED records write; chunk-local
//   offsets -> histmat.
// Blocks [FILLB, FILLB+XWB): xwsh[r] = f16(x[r] @ W) via MFMA, B-fragments
//   loaded directly from global W (L1-resident) with f32->f16 convert.
//   (NO LDS staging of W: static LDS is unioned across branches and would
//    cut the fill branch's occupancy — measured −4.5 µs in R21.)
// record = (row << 8) | (col & 255)
// ===========================================================================
__global__ __launch_bounds__(512)
void fill_xw_kernel(const int* __restrict__ row, const int* __restrict__ col,
                    int* __restrict__ histmat, unsigned int* __restrict__ records,
                    const float* __restrict__ x, const float* __restrict__ W,
                    ushort_t* __restrict__ xwsh) {
    __shared__ unsigned int stage[CHUNK];    // 12.8 KB
    __shared__ int hist[NBUK];
    __shared__ int lcur[NBUK];
    __shared__ int wsum[8];
    if (blockIdx.x < FILLB) {
        int t = threadIdx.x, blk = blockIdx.x;
        int lane = t & 63, wv = t >> 6;
        for (int bb = t; bb < NBUK; bb += 512) hist[bb] = 0;
        __syncthreads();
        int e0 = blk * CHUNK;
        for (int j = t; j < CHUNK; j += 512) atomicAdd(&hist[col[e0 + j] >> 8], 1);
        __syncthreads();
        int own = (t < NBUK) ? hist[t] : 0;
        int inc = wave_scan(own, lane);
        if (lane == 63) wsum[wv] = inc;
        __syncthreads();
        int wpre = 0;
#pragma unroll
        for (int w = 0; w < 8; ++w) wpre += (w < wv) ? wsum[w] : 0;
        int excl = inc + wpre - own;           // exclusive prefix; t==NBUK -> 3200
        if (t <= NBUK) {
            histmat[(size_t)blk * (NBUK + 1) + t] = excl;
            if (t < NBUK) lcur[t] = excl;
        }
        __syncthreads();
        for (int j = t; j < CHUNK; j += 512) {
            int e = e0 + j;
            int c = col[e];                    // L1-hot re-read
            int slot = atomicAdd(&lcur[c >> 8], 1);
            stage[slot] = ((unsigned int)row[e] << 8) | (unsigned int)(c & 255);
        }
        __syncthreads();
        uint4* dst = (uint4*)(records + (size_t)blk * CHUNK);
        const uint4* srcv = (const uint4*)stage;
        for (int j = t; j < CHUNK / 4; j += 512) dst[j] = srcv[j];
        return;
    }
    // ---- xw part: 8 waves x 16 rows ----
    int t = threadIdx.x;
    int wv = t >> 6, lane = t & 63;
    int wtile = (blockIdx.x - FILLB) * 8 + wv;
    if (wtile >= NTILES) return;           // uniform per wave
    int r0 = wtile * 16;
    int rowi = lane & 15;                  // A-row / B-col / D-col
    int kg = lane >> 4;                    // k-group (0..3)

    // B fragments straight from W (16 KB, L1-resident): W[k][c], k-run of 8
    f16x8 bfrag[2][4];
#pragma unroll
    for (int t2 = 0; t2 < 2; ++t2) {
        int c = t2 * 16 + rowi;
#pragma unroll
        for (int ss = 0; ss < 4; ++ss) {
            const float* Wp = W + (size_t)(ss * 32 + kg * 8) * DOUT + c;
            f16x8 bf;
#pragma unroll
            for (int i = 0; i < 8; ++i) bf[i] = (_Float16)Wp[i * DOUT];
            bfrag[t2][ss] = bf;
        }
    }

    const float* __restrict__ xr = x + (size_t)(r0 + rowi) * DIN;
    float4 xa[8];
#pragma unroll
    for (int ss = 0; ss < 4; ++ss) {
        xa[2 * ss]     = *(const float4*)(xr + ss * 32 + kg * 8);
        xa[2 * ss + 1] = *(const float4*)(xr + ss * 32 + kg * 8 + 4);
    }
    f16x8 afrag[4];
#pragma unroll
    for (int ss = 0; ss < 4; ++ss) {
        f16x8 a;
        a[0] = (_Float16)xa[2 * ss].x;     a[1] = (_Float16)xa[2 * ss].y;
        a[2] = (_Float16)xa[2 * ss].z;     a[3] = (_Float16)xa[2 * ss].w;
        a[4] = (_Float16)xa[2 * ss + 1].x; a[5] = (_Float16)xa[2 * ss + 1].y;
        a[6] = (_Float16)xa[2 * ss + 1].z; a[7] = (_Float16)xa[2 * ss + 1].w;
        afrag[ss] = a;
    }

    f32x4 acc0 = {0.f, 0.f, 0.f, 0.f};
    f32x4 acc1 = {0.f, 0.f, 0.f, 0.f};
#pragma unroll
    for (int ss = 0; ss < 4; ++ss) {
        acc0 = __builtin_amdgcn_mfma_f32_16x16x32_f16(afrag[ss], bfrag[0][ss], acc0, 0, 0, 0);
        acc1 = __builtin_amdgcn_mfma_f32_16x16x32_f16(afrag[ss], bfrag[1][ss], acc1, 0, 0, 0);
    }

#pragma unroll
    for (int j = 0; j < 4; ++j) {
        int orow = r0 + kg * 4 + j;
        xwsh[(size_t)orow * DOUT + rowi]      = f2h_u(acc0[j]);
        xwsh[(size_t)orow * DOUT + 16 + rowi] = f2h_u(acc1[j]);
    }
}

// ===========================================================================
// k2: per-bucket sort. Bucket b owns fixed region srcs[b*CAP_PAD..].
// Clamp-batched segment gather (8 reads in flight), per-wave privatized
// node histogram, 1-barrier wave scans, LDS counting sort into an
// 8-ALIGNED-PER-NODE padded layout (pads zero-filled), offe/dis,
// xwsh-scale epilogue. 391 blocks x 512.
// ===========================================================================
__global__ __launch_bounds__(512)
void sort_kernel(const int* __restrict__ histmat,
                 const unsigned int* __restrict__ records,
                 int* __restrict__ srcs, float* __restrict__ dis,
                 int2* __restrict__ offe, ushort_t* __restrict__ xwsh) {
    __shared__ unsigned int stage[CAP];  // 32 KB
    __shared__ int whist[8][256];        // 8 KB, per-wave private histograms
    __shared__ int lcur[256];
    __shared__ float disL[256];
    __shared__ int wsum[8];
    __shared__ int wsum2[4];
    int b = blockIdx.x, t = threadIdx.x;
    int lane = t & 63, wv = t >> 6;
    int s_off = 0, len = 0;
    if (t < FILLB) {
        s_off = histmat[(size_t)t * (NBUK + 1) + b];
        len = histmat[(size_t)t * (NBUK + 1) + b + 1] - s_off;
    }
    for (int i = t; i < 8 * 256; i += 512) ((int*)whist)[i] = 0;
    // 1-barrier scan of segment lengths
    int inc = wave_scan(len, lane);
    if (lane == 63) wsum[wv] = inc;
    __syncthreads();
    int wpre = 0, cnt = 0;
#pragma unroll
    for (int w = 0; w < 8; ++w) {
        wpre += (w < wv) ? wsum[w] : 0;
        cnt += wsum[w];
    }
    int pos = inc + wpre - len;

    // clamp-batched gather: 8 scattered reads in flight per thread
    const unsigned int* seg = records + (size_t)t * CHUNK + s_off;
    for (int k = 0; k < len; k += 8) {
        unsigned int v[8];
#pragma unroll
        for (int u = 0; u < 8; ++u) {
            int idx = (k + u < len) ? (k + u) : (len - 1);
            v[u] = seg[idx];
        }
#pragma unroll
        for (int u = 0; u < 8; ++u)
            if (k + u < len) {
                stage[pos + k + u] = v[u];
                atomicAdd(&whist[wv][v[u] & 255u], 1);
            }
    }
    __syncthreads();

    int d = 0;
    if (t < 256) {
#pragma unroll
        for (int w = 0; w < 8; ++w) d += whist[w][t];
    }
    int pd = (d + 7) & ~7;               // padded degree (8-aligned region)
    // 1-barrier scan over the 256 padded degrees (4 waves)
    int inc2 = wave_scan((t < 256) ? pd : 0, lane);
    if (t < 256 && lane == 63) wsum2[wv] = inc2;
    __syncthreads();
    int sbase = b * CAP_PAD;
    if (t < 256) {
        int wpre2 = 0;
#pragma unroll
        for (int w = 0; w < 4; ++w) wpre2 += (w < wv) ? wsum2[w] : 0;
        int excl = inc2 + wpre2 - pd;    // 8-aligned start (relative)
        float dv = rsqrtf((float)(d + 1));
        disL[t] = dv;
        int n = (b << 8) + t;
        if (n < NN) {
            dis[n] = dv;
            offe[n] = make_int2(sbase + excl, sbase + excl + d);
        }
        lcur[t] = excl;
        // zero-fill the pad slots (safe index 0 for masked int4 gathers)
        for (int k = d; k < pd; ++k) srcs[sbase + excl + k] = 0;
    }
    __syncthreads();
    for (int j = t; j < cnt; j += 512) {
        unsigned int rec = stage[j];
        int slot = atomicAdd(&lcur[rec & 255u], 1);
        srcs[sbase + slot] = (int)(rec >> 8);
    }
    // epilogue: scale this bucket's xwsh rows by dis (coalesced u32 r/m/w)
    int n0 = b << 8;
    for (int idx = t; idx < 256 * 16; idx += 512) {
        int loc = idx >> 4;
        int n = n0 + loc;
        if (n >= NN) break;
        uint_t* p = (uint_t*)(xwsh + ((size_t)n << 5)) + (idx & 15);
        uint_t v = *p;
        float dv = disL[loc];
        float lo = h2f((ushort_t)(v & 0xffffu)) * dv;
        float hi = h2f((ushort_t)(v >> 16)) * dv;
        *p = (uint_t)f2h_u(lo) | ((uint_t)f2h_u(hi) << 16);
    }
}

// ===========================================================================
// k3: aggregate, zero-reduce layout, 8-wide batched. Half-wave (32 lanes)
// = one node; lane owns one output dim. Per round: TWO aligned int4 loads
// fetch the 8 srcs (regions 8-aligned; pads zero -> safe), 8 independent
// xwsh gathers, masked accumulate. offs/ends as one int2 load.
// ===========================================================================
__global__ __launch_bounds__(256)
void aggregate_kernel(const int2* __restrict__ offe, const int* __restrict__ srcs,
                      const float* __restrict__ dis, const ushort_t* __restrict__ xwsh,
                      const float* __restrict__ bias, float* __restrict__ out) {
    int gw = (int)((blockIdx.x * (long long)blockDim.x + threadIdx.x) >> 6);
    int half = (threadIdx.x >> 5) & 1;
    int wid = gw * 2 + half;
    if (wid >= NN) return;
    int d = threadIdx.x & 31;

    int2 se = offe[wid];
    int s = se.x, e = se.y;
    float acc = h2f(xwsh[((size_t)wid << 5) + d]);   // self-loop (scaled)
    for (int i = s; i < e; i += 8) {
        int4 ra = *(const int4*)(srcs + i);          // 8-aligned region
        int4 rb = *(const int4*)(srcs + i + 4);
        int r[8];
        r[0] = ra.x; r[1] = ra.y; r[2] = ra.z; r[3] = ra.w;
        r[4] = rb.x; r[5] = rb.y; r[6] = rb.z; r[7] = rb.w;
        ushort_t u[8];
#pragma unroll
        for (int k = 0; k < 8; ++k) u[k] = xwsh[((size_t)r[k] << 5) + d];
#pragma unroll
        for (int k = 0; k < 8; ++k) acc += (i + k < e) ? h2f(u[k]) : 0.f;
    }
    out[((size_t)wid << 5) + d] = dis[wid] * acc + bias[d];
}

// ===========================================================================
// Fallback path (R1) if workspace is too small
// ===========================================================================
__global__ void deg_count_kernel(const int* __restrict__ col, int* __restrict__ deg) {
    int e = blockIdx.x * blockDim.x + threadIdx.x;
    if (e < NE) atomicAdd(&deg[col[e]], 1);
}
__global__ void dis_kernel(const int* __restrict__ deg, float* __restrict__ dis) {
    int i = blockIdx.x * blockDim.x + threadIdx.x;
    if (i < NN) dis[i] = rsqrtf((float)(deg[i] + 1));
}
__global__ void xw_init_kernel(const float* __restrict__ x, const float* __restrict__ W,
                               const float* __restrict__ b, const float* __restrict__ dis,
                               float* __restrict__ xw, float* __restrict__ out) {
    __shared__ float Ws[DIN * DOUT];
    for (int i = threadIdx.x; i < DIN * DOUT; i += blockDim.x) Ws[i] = W[i];
    __syncthreads();
    int idx = blockIdx.x * blockDim.x + threadIdx.x;
    if (idx >= NN * DOUT) return;
    int n = idx >> 5;
    int d = idx & (DOUT - 1);
    const float* xr = x + (long long)n * DIN;
    float acc = 0.f;
#pragma unroll
    for (int k = 0; k < DIN; ++k) acc += xr[k] * Ws[k * DOUT + d];
    xw[idx] = acc;
    float di = dis[n];
    out[idx] = di * di * acc + b[d];
}
__global__ void scatter_kernel(const int* __restrict__ row, const int* __restrict__ col,
                               const float* __restrict__ dis, const float* __restrict__ xw,
                               float* __restrict__ out) {
    long long idx = (long long)blockIdx.x * blockDim.x + threadIdx.x;
    if (idx >= (long long)NE * DOUT) return;
    int e = (int)(idx >> 5);
    int d = (int)(idx & (DOUT - 1));
    int r = row[e];
    int c = col[e];
    atomicAdd(&out[c * DOUT + d], dis[r] * dis[c] * xw[r * DOUT + d]);
}

// ===========================================================================
extern "C" void kernel_launch(void* const* d_in, const int* in_sizes, int n_in,
                              void* d_out, int out_size, void* d_ws, size_t ws_size,
                              hipStream_t stream) {
    const float* x  = (const float*)d_in[0];
    const int*   ei = (const int*)d_in[1];
    const float* W  = (const float*)d_in[2];
    const float* b  = (const float*)d_in[3];
    float* out = (float*)d_out;

    const int* row = ei;       // edge_index[0] = source
    const int* col = ei + NE;  // edge_index[1] = target

    char* ws = (char*)d_ws;
    int*          histmat = (int*)(ws + 0);          //   500*392*4 = 784,000 B
    int2*         offe    = (int2*)(ws + 784128);    //   800,000 B
    float*        dis     = (float*)(ws + 1584128);  //   400,000 B
    unsigned int* records = (unsigned int*)(ws + 1984128);  // 6,400,000 B
    int*          srcs    = (int*)(ws + 8384128);    // 391*6144*4 = 9,609,216 B
    ushort_t*     xwsh    = (ushort_t*)(ws + 17993344);     // 6,400,000 B
    const size_t WS_NEEDED = 24393344ull;

    if (ws_size >= WS_NEEDED) {
        fill_xw_kernel<<<FILLB + XWB, 512, 0, stream>>>(row, col, histmat,
                                                        records, x, W, xwsh);
        sort_kernel<<<NBUK, 512, 0, stream>>>(histmat, records, srcs, dis,
                                              offe, xwsh);
        {
            long long waves = (NN + 1) / 2;             // 2 nodes per wave
            int bl = (int)((waves + 3) / 4);            // 4 waves per block
            aggregate_kernel<<<bl, 256, 0, stream>>>(offe, srcs, dis, xwsh, b, out);
        }
    } else {
        // fallback: atomic scatter path
        int* deg2 = (int*)(ws + 0);
        float* dis2 = (float*)(ws + 400128);
        float* xw = (float*)(ws + 800256);
        hipMemsetAsync(deg2, 0, NN * sizeof(int), stream);
        {
            int th = 256, bl = (NE + th - 1) / th;
            deg_count_kernel<<<bl, th, 0, stream>>>(col, deg2);
        }
        {
            int th = 256, bl = (NN + th - 1) / th;
            dis_kernel<<<bl, th, 0, stream>>>(deg2, dis2);
        }
        {
            long long total = (long long)NN * DOUT;
            int bl = (int)((total + 255) / 256);
            xw_init_kernel<<<bl, 256, 0, stream>>>(x, W, b, dis2, xw, out);
        }
        {
            long long total = (long long)NE * DOUT;
            int bl = (int)((total + 255) / 256);
            scatter_kernel<<<bl, 256, 0, stream>>>(row, col, dis2, xw, out);
        }
    }
}